// Round 3
// baseline (517.710 us; speedup 1.0000x reference)
//
#include <hip/hip_runtime.h>
#include <cstdint>
#include <cstddef>

// Problem dims (fixed)
#define CDIM 8192
#define NDIM 1024   // H*W
#define C8D  1024
#define MSTACK 10240  // 8192 (v) + 1024 (q) + 1024 (k)

typedef __bf16 bf16_t;
typedef __bf16 bf16x8 __attribute__((ext_vector_type(8)));
typedef __bf16 bf16x4 __attribute__((ext_vector_type(4)));
typedef float  f32x4  __attribute__((ext_vector_type(4)));

__device__ __forceinline__ void gload_lds16(const void* g, void* l) {
    __builtin_amdgcn_global_load_lds((const __attribute__((address_space(1))) void*)g,
                                     (__attribute__((address_space(3))) void*)l, 16, 0, 0);
}

// ---------------------------------------------------------------------------
// fp32 -> bf16 elementwise convert, 8 elems/thread, grid-stride
__global__ __launch_bounds__(256) void cvt_bf16_k(const float* __restrict__ in,
                                                  bf16_t* __restrict__ out, int n8) {
    int idx = blockIdx.x * 256 + threadIdx.x;
    int stride = gridDim.x * 256;
    for (int i = idx; i < n8; i += stride) {
        size_t off = (size_t)i * 8;
        float4 a = *(const float4*)(in + off);
        float4 b = *(const float4*)(in + off + 4);
        bf16x8 o = { (__bf16)a.x, (__bf16)a.y, (__bf16)a.z, (__bf16)a.w,
                     (__bf16)b.x, (__bf16)b.y, (__bf16)b.z, (__bf16)b.w };
        *(bf16x8*)(out + off) = o;
    }
}

// ---------------------------------------------------------------------------
// x (C=8192, N=1024) fp32 -> xT (N, C) bf16, LDS-tiled transpose
__global__ __launch_bounds__(256) void transpose_cvt_x(const float* __restrict__ x,
                                                       bf16_t* __restrict__ xT) {
    __shared__ float t[32][33];
    const int n0 = blockIdx.x * 32, c0 = blockIdx.y * 32;
    const int tx = threadIdx.x, ty = threadIdx.y; // block (32,8)
    #pragma unroll
    for (int i = 0; i < 4; ++i)
        t[ty + i * 8][tx] = x[(size_t)(c0 + ty + i * 8) * NDIM + n0 + tx];
    __syncthreads();
    #pragma unroll
    for (int i = 0; i < 4; ++i)
        xT[(size_t)(n0 + ty + i * 8) * CDIM + c0 + tx] = (__bf16)t[tx][ty + i * 8];
}

// ---------------------------------------------------------------------------
// Mega-GEMM, split-K x2: partial[z][i][j] = sum_{k in half z} A[i,k]*B[j,k],
// A = [Wv;Wq;Wk] stacked (M=10240), B = xT. 128x128 tile, BK=32, 4 waves,
// XCD-swizzled xy grid; grid (8, 80, 2) = 1280 blocks (5/CU). Raw fp32 out.
__global__ __launch_bounds__(256) void mega_gemm(
    const bf16_t* __restrict__ Wv, const bf16_t* __restrict__ Wq,
    const bf16_t* __restrict__ Wk, const bf16_t* __restrict__ Bx,
    float* __restrict__ pp)
{
    const int z = blockIdx.z;
    // XCD-aware bijective swizzle over the xy plane (nwg = 640, %8 == 0)
    const int lin = blockIdx.y * 8 + blockIdx.x;
    const int tile = (lin & 7) * 80 + (lin >> 3);
    const int row0 = (tile >> 3) * 128;
    const int col0 = (tile & 7) * 128;

    const bf16_t* A; int arow;
    if (row0 < 8192)      { A = Wv; arow = row0; }
    else if (row0 < 9216) { A = Wq; arow = row0 - 8192; }
    else                  { A = Wk; arow = row0 - 9216; }

    const int tid = threadIdx.x;
    __shared__ __align__(16) bf16_t As[128 * 32];
    __shared__ __align__(16) bf16_t Bs[128 * 32];

    const int lane = tid & 63;
    const int w    = tid >> 6;
    const int wm   = (w >> 1) * 64;
    const int wn   = (w & 1) * 64;
    const int lr   = lane & 15;
    const int kg   = (lane >> 4) * 8;

    f32x4 acc[4][4];
    #pragma unroll
    for (int a_ = 0; a_ < 4; ++a_)
        #pragma unroll
        for (int b_ = 0; b_ < 4; ++b_)
            acc[a_][b_] = (f32x4){0.f, 0.f, 0.f, 0.f};

    const int eA = tid * 8;
    const int eB = (256 + tid) * 8;
    const int rA = eA >> 5, cA = eA & 31;
    const int rB = eB >> 5, cB = eB & 31;

    const int kb0 = z * (CDIM / 2);
    const int kb1 = kb0 + (CDIM / 2);
    for (int kb = kb0; kb < kb1; kb += 32) {
        gload_lds16(A + (size_t)(arow + rA) * CDIM + kb + cA, As + eA);
        gload_lds16(A + (size_t)(arow + rB) * CDIM + kb + cB, As + eB);
        gload_lds16(Bx + (size_t)(col0 + rA) * CDIM + kb + cA, Bs + eA);
        gload_lds16(Bx + (size_t)(col0 + rB) * CDIM + kb + cB, Bs + eB);
        __syncthreads();

        bf16x8 av[4], bv[4];
        #pragma unroll
        for (int mi = 0; mi < 4; ++mi)
            av[mi] = *(const bf16x8*)(As + (wm + mi * 16 + lr) * 32 + kg);
        #pragma unroll
        for (int ni = 0; ni < 4; ++ni)
            bv[ni] = *(const bf16x8*)(Bs + (wn + ni * 16 + lr) * 32 + kg);

        #pragma unroll
        for (int mi = 0; mi < 4; ++mi)
            #pragma unroll
            for (int ni = 0; ni < 4; ++ni)
                acc[mi][ni] = __builtin_amdgcn_mfma_f32_16x16x32_bf16(
                    av[mi], bv[ni], acc[mi][ni], 0, 0, 0);
        __syncthreads();
    }

    float* pz = pp + (size_t)z * MSTACK * NDIM;
    const int cr = (lane >> 4) * 4;  // C/D: col = lane&15, row = (lane>>4)*4 + r
    #pragma unroll
    for (int mi = 0; mi < 4; ++mi) {
        #pragma unroll
        for (int ni = 0; ni < 4; ++ni) {
            const int j = col0 + wn + ni * 16 + lr;
            #pragma unroll
            for (int r = 0; r < 4; ++r) {
                const int gi = row0 + wm + mi * 16 + cr + r;
                pz[(size_t)gi * NDIM + j] = acc[mi][ni][r];
            }
        }
    }
}

// ---------------------------------------------------------------------------
// Reduce the two K-halves + apply BN scale/shift; emit v (bf16), q_on/k_on (fp32).
__global__ __launch_bounds__(256) void reduce_mega(
    const float* __restrict__ pp, bf16_t* __restrict__ v_out,
    float* __restrict__ q_out, float* __restrict__ k_out,
    const float* __restrict__ vs, const float* __restrict__ vh,
    const float* __restrict__ qs, const float* __restrict__ qh,
    const float* __restrict__ ks_, const float* __restrict__ kh)
{
    const size_t NU = (size_t)MSTACK * NDIM / 4;    // float4 units
    const size_t stride = (size_t)gridDim.x * 256;
    for (size_t u = (size_t)blockIdx.x * 256 + threadIdx.x; u < NU; u += stride) {
        float4 a = ((const float4*)pp)[u];
        float4 b = ((const float4*)pp)[u + NU];
        const int i  = (int)(u >> 8);          // row (1024/4 = 256 units per row)
        const int jj = ((int)u & 255) * 4;
        float sx = a.x + b.x, sy = a.y + b.y, sz = a.z + b.z, sw = a.w + b.w;
        if (i < 8192) {
            const float sc = vs[i], sh = vh[i];
            bf16x4 o = { (__bf16)(sx * sc + sh), (__bf16)(sy * sc + sh),
                         (__bf16)(sz * sc + sh), (__bf16)(sw * sc + sh) };
            *(bf16x4*)(v_out + (size_t)i * NDIM + jj) = o;
        } else if (i < 9216) {
            const int il = i - 8192;
            const float sc = qs[il], sh = qh[il];
            float4 o = { sx * sc + sh, sy * sc + sh, sz * sc + sh, sw * sc + sh };
            *(float4*)(q_out + (size_t)il * NDIM + jj) = o;
        } else {
            const int il = i - 9216;
            const float sc = ks_[il], sh = kh[il];
            float4 o = { sx * sc + sh, sy * sc + sh, sz * sc + sh, sw * sc + sh };
            *(float4*)(k_out + (size_t)il * NDIM + jj) = o;
        }
    }
}

// ---------------------------------------------------------------------------
// bt-GEMM: C[i,j] = sum_k A[i,k] * B[j,k]. XCD-swizzled xy grid; optional
// split-K via gridDim.z (each z writes its own partial plane C + z*M*N).
// EPI: 2 = v*(1/1023)/(e0[j]*e1[j])  -> ppmcc partial
//      3 = gs[0]*v + e0[i*N+j]       -> gamma*out + x
template <int EPI, typename OutT>
__global__ __launch_bounds__(256) void gemm_bt(
    const bf16_t* __restrict__ A, const bf16_t* __restrict__ B,
    OutT* __restrict__ C, int M, int N, int K,
    const float* __restrict__ e0, const float* __restrict__ e1,
    const float* __restrict__ gs)
{
    const int gx = gridDim.x;
    const int nwg = gx * gridDim.y;
    const int lin = blockIdx.y * gx + blockIdx.x;
    int tile = lin;
    if ((nwg & 7) == 0) tile = (lin & 7) * (nwg >> 3) + (lin >> 3);
    const int row0 = (tile / gx) * 128;
    const int col0 = (tile % gx) * 128;

    const int Ks  = K / gridDim.z;
    const int kb0 = blockIdx.z * Ks;
    OutT* Cz = C + (size_t)blockIdx.z * M * N;

    const int tid = threadIdx.x;
    __shared__ __align__(16) bf16_t As[128 * 32];
    __shared__ __align__(16) bf16_t Bs[128 * 32];

    const int lane = tid & 63;
    const int w    = tid >> 6;
    const int wm   = (w >> 1) * 64;
    const int wn   = (w & 1) * 64;
    const int lr   = lane & 15;
    const int kg   = (lane >> 4) * 8;

    f32x4 acc[4][4];
    #pragma unroll
    for (int a_ = 0; a_ < 4; ++a_)
        #pragma unroll
        for (int b_ = 0; b_ < 4; ++b_)
            acc[a_][b_] = (f32x4){0.f, 0.f, 0.f, 0.f};

    const int eA = tid * 8;
    const int eB = (256 + tid) * 8;
    const int rA = eA >> 5, cA = eA & 31;
    const int rB = eB >> 5, cB = eB & 31;

    for (int kb = kb0; kb < kb0 + Ks; kb += 32) {
        gload_lds16(A + (size_t)(row0 + rA) * K + kb + cA, As + eA);
        gload_lds16(A + (size_t)(row0 + rB) * K + kb + cB, As + eB);
        gload_lds16(B + (size_t)(col0 + rA) * K + kb + cA, Bs + eA);
        gload_lds16(B + (size_t)(col0 + rB) * K + kb + cB, Bs + eB);
        __syncthreads();

        bf16x8 av[4], bv[4];
        #pragma unroll
        for (int mi = 0; mi < 4; ++mi)
            av[mi] = *(const bf16x8*)(As + (wm + mi * 16 + lr) * 32 + kg);
        #pragma unroll
        for (int ni = 0; ni < 4; ++ni)
            bv[ni] = *(const bf16x8*)(Bs + (wn + ni * 16 + lr) * 32 + kg);

        #pragma unroll
        for (int mi = 0; mi < 4; ++mi)
            #pragma unroll
            for (int ni = 0; ni < 4; ++ni)
                acc[mi][ni] = __builtin_amdgcn_mfma_f32_16x16x32_bf16(
                    av[mi], bv[ni], acc[mi][ni], 0, 0, 0);
        __syncthreads();
    }

    float g = 0.f;
    if (EPI == 3) g = gs[0];
    const int cr = (lane >> 4) * 4;
    #pragma unroll
    for (int mi = 0; mi < 4; ++mi) {
        #pragma unroll
        for (int ni = 0; ni < 4; ++ni) {
            const int j = col0 + wn + ni * 16 + lr;
            float s0 = 0.f, s1 = 0.f;
            if (EPI == 2) { s0 = e0[j]; s1 = e1[j]; }
            #pragma unroll
            for (int r = 0; r < 4; ++r) {
                const int i = row0 + wm + mi * 16 + cr + r;
                float v = acc[mi][ni][r];
                if (EPI == 2)      v = v * (1.0f / 1023.0f) / (s0 * s1);
                else if (EPI == 3) v = g * v + e0[(size_t)i * N + j];
                Cz[(size_t)i * N + j] = (OutT)v;
            }
        }
    }
}

// ---------------------------------------------------------------------------
// Row mean/std (ddof=0) of q_on / k_on (each 1024 x 1024 fp32). One wave/row.
__global__ __launch_bounds__(256) void rowstats(
    const float* __restrict__ Q, const float* __restrict__ Km,
    float* __restrict__ qmean, float* __restrict__ qstd,
    float* __restrict__ kmean, float* __restrict__ kstd)
{
    const int wid  = blockIdx.x * 4 + (threadIdx.x >> 6);
    const int lane = threadIdx.x & 63;
    const float* src = (wid < 1024) ? (Q + (size_t)wid * NDIM)
                                    : (Km + (size_t)(wid - 1024) * NDIM);
    float s = 0.f, s2 = 0.f;
    #pragma unroll
    for (int p = 0; p < 4; ++p) {
        float4 v = *(const float4*)(src + p * 256 + lane * 4);
        s  += v.x + v.y + v.z + v.w;
        s2 += v.x * v.x + v.y * v.y + v.z * v.z + v.w * v.w;
    }
    #pragma unroll
    for (int o = 32; o; o >>= 1) { s += __shfl_xor(s, o); s2 += __shfl_xor(s2, o); }
    if (lane == 0) {
        float m   = s / 1024.f;
        float var = fmaxf(s2 / 1024.f - m * m, 0.f);
        if (wid < 1024) { qmean[wid] = m; qstd[wid] = sqrtf(var); }
        else            { kmean[wid - 1024] = m; kstd[wid - 1024] = sqrtf(var); }
    }
}

// ---------------------------------------------------------------------------
// Center by row mean, transpose (o,n)->(n,o), convert bf16. z selects q/k.
__global__ __launch_bounds__(256) void center_tr(
    const float* __restrict__ Q, const float* __restrict__ qmu, bf16_t* __restrict__ qc,
    const float* __restrict__ Km, const float* __restrict__ kmu, bf16_t* __restrict__ kc)
{
    __shared__ float t[32][33];
    const float* M  = blockIdx.z ? Km  : Q;
    const float* mu = blockIdx.z ? kmu : qmu;
    bf16_t* O       = blockIdx.z ? kc  : qc;
    const int o0 = blockIdx.y * 32, n0 = blockIdx.x * 32;
    const int tx = threadIdx.x, ty = threadIdx.y; // block (32,8)
    #pragma unroll
    for (int i = 0; i < 4; ++i) {
        const int o = o0 + ty + i * 8;
        t[ty + i * 8][tx] = M[(size_t)o * NDIM + n0 + tx] - mu[o];
    }
    __syncthreads();
    #pragma unroll
    for (int i = 0; i < 4; ++i)
        O[(size_t)(n0 + ty + i * 8) * C8D + o0 + tx] = (__bf16)t[tx][ty + i * 8];
}

// ---------------------------------------------------------------------------
// Row softmax over the sum of 4 split-K partial P planes -> bf16 A0.
__global__ __launch_bounds__(256) void softmax_rows(const float* __restrict__ P,
                                                    bf16_t* __restrict__ O) {
    const int row = blockIdx.x;
    const int tid = threadIdx.x;
    const size_t PL = (size_t)NDIM * NDIM / 4;   // plane size in float4 units
    const size_t u  = (size_t)row * (NDIM / 4) + tid;
    const float4* B = (const float4*)P;
    float4 p0 = B[u], p1 = B[u + PL], p2 = B[u + 2 * PL], p3 = B[u + 3 * PL];
    float4 v = { p0.x + p1.x + p2.x + p3.x, p0.y + p1.y + p2.y + p3.y,
                 p0.z + p1.z + p2.z + p3.z, p0.w + p1.w + p2.w + p3.w };
    float mx = fmaxf(fmaxf(v.x, v.y), fmaxf(v.z, v.w));
    #pragma unroll
    for (int o = 32; o; o >>= 1) mx = fmaxf(mx, __shfl_xor(mx, o));
    __shared__ float red[8];
    const int w = tid >> 6, lane = tid & 63;
    if (lane == 0) red[w] = mx;
    __syncthreads();
    mx = fmaxf(fmaxf(red[0], red[1]), fmaxf(red[2], red[3]));
    float e0 = __expf(v.x - mx), e1 = __expf(v.y - mx);
    float e2 = __expf(v.z - mx), e3 = __expf(v.w - mx);
    float s = e0 + e1 + e2 + e3;
    #pragma unroll
    for (int o = 32; o; o >>= 1) s += __shfl_xor(s, o);
    if (lane == 0) red[4 + w] = s;
    __syncthreads();
    s = red[4] + red[5] + red[6] + red[7];
    const float inv = 1.0f / s;
    bf16x4 o4 = { (__bf16)(e0 * inv), (__bf16)(e1 * inv),
                  (__bf16)(e2 * inv), (__bf16)(e3 * inv) };
    ((bf16x4*)(O + (size_t)row * NDIM))[tid] = o4;
}

// ---------------------------------------------------------------------------
extern "C" void kernel_launch(void* const* d_in, const int* in_sizes, int n_in,
                              void* d_out, int out_size, void* d_ws, size_t ws_size,
                              hipStream_t stream)
{
    const float* x       = (const float*)d_in[0];
    const float* Wq      = (const float*)d_in[1];
    const float* Wk      = (const float*)d_in[2];
    const float* Wv      = (const float*)d_in[3];
    const float* q_scale = (const float*)d_in[4];
    const float* q_shift = (const float*)d_in[5];
    const float* k_scale = (const float*)d_in[6];
    const float* k_shift = (const float*)d_in[7];
    const float* v_scale = (const float*)d_in[8];
    const float* v_shift = (const float*)d_in[9];
    const float* gamma   = (const float*)d_in[10];
    float* out = (float*)d_out;

    // workspace layout (~294 MB); U region reuses the mega partial buffer.
    char* w = (char*)d_ws;
    bf16_t* Wv_b = (bf16_t*)w; w += (size_t)CDIM * CDIM * 2;
    bf16_t* Wq_b = (bf16_t*)w; w += (size_t)C8D  * CDIM * 2;
    bf16_t* Wk_b = (bf16_t*)w; w += (size_t)C8D  * CDIM * 2;
    bf16_t* xT   = (bf16_t*)w; w += (size_t)NDIM * CDIM * 2;
    bf16_t* v_b  = (bf16_t*)w; w += (size_t)CDIM * NDIM * 2;
    float*  q_on = (float*) w; w += (size_t)C8D * NDIM * 4;
    float*  k_on = (float*) w; w += (size_t)C8D * NDIM * 4;
    float*  qmean = (float*)w; w += C8D * 4;
    float*  qstd  = (float*)w; w += C8D * 4;
    float*  kmean = (float*)w; w += C8D * 4;
    float*  kstd  = (float*)w; w += C8D * 4;
    // U region: mega partials (84 MB), later reused for P partials + qc/kc/A0
    char* U = w;
    float*  pp = (float*)U;                                  // 2 x 10240 x 1024 fp32
    float*  P  = (float*)U;                                  // 4 x 1024 x 1024 fp32
    bf16_t* qc = (bf16_t*)(U + (size_t)4 * NDIM * NDIM * 4);
    bf16_t* kc = qc + (size_t)NDIM * C8D;
    bf16_t* A0 = kc + (size_t)NDIM * C8D;

    // 1. converts
    cvt_bf16_k<<<2048, 256, 0, stream>>>(Wv, Wv_b, (int)((size_t)CDIM * CDIM / 8));
    cvt_bf16_k<<<2048, 256, 0, stream>>>(Wq, Wq_b, C8D * CDIM / 8);
    cvt_bf16_k<<<2048, 256, 0, stream>>>(Wk, Wk_b, C8D * CDIM / 8);
    transpose_cvt_x<<<dim3(NDIM / 32, CDIM / 32), dim3(32, 8), 0, stream>>>(x, xT);

    // 2. mega-GEMM split-K x2: raw partials (1280 blocks)
    mega_gemm<<<dim3(8, MSTACK / 128, 2), 256, 0, stream>>>(
        Wv_b, Wq_b, Wk_b, xT, pp);

    // 3. reduce K-halves + BN scale/shift -> v_b (bf16), q_on, k_on (fp32)
    reduce_mega<<<2560, 256, 0, stream>>>(
        pp, v_b, q_on, k_on, v_scale, v_shift, q_scale, q_shift, k_scale, k_shift);

    // 4. row stats of q_on / k_on (2048 waves)
    rowstats<<<512, 256, 0, stream>>>(q_on, k_on, qmean, qstd, kmean, kstd);

    // 5. center + transpose + bf16
    center_tr<<<dim3(32, 32, 2), dim3(32, 8), 0, stream>>>(
        q_on, qmean, qc, k_on, kmean, kc);

    // 6. P[z] = (qc . kc^T)_z / 1023 / (qstd[j] * kstd[j]), split-K x4 (256 blocks)
    gemm_bt<2, float><<<dim3(NDIM / 128, NDIM / 128, 4), 256, 0, stream>>>(
        qc, kc, P, NDIM, NDIM, C8D, qstd, kstd, nullptr);

    // 7. row softmax over summed partials -> A0 (bf16)
    softmax_rows<<<NDIM, 256, 0, stream>>>(P, A0);

    // 8. out = gamma * (v . A0^T) + x
    gemm_bt<3, float><<<dim3(NDIM / 128, CDIM / 128, 1), 256, 0, stream>>>(
        v_b, A0, out, CDIM, NDIM, NDIM, x, x, gamma);
}

// Round 4
// 418.830 us; speedup vs baseline: 1.2361x; 1.2361x over previous
//
#include <hip/hip_runtime.h>
#include <cstdint>
#include <cstddef>

// Problem dims (fixed)
#define CDIM 8192
#define NDIM 1024   // H*W
#define C8D  1024
#define MSTACK 10240  // 8192 (v) + 1024 (q) + 1024 (k)

typedef __bf16 bf16_t;
typedef __bf16 bf16x8 __attribute__((ext_vector_type(8)));
typedef __bf16 bf16x4 __attribute__((ext_vector_type(4)));
typedef float  f32x4  __attribute__((ext_vector_type(4)));

__device__ __forceinline__ void gload_lds16(const void* g, void* l) {
    __builtin_amdgcn_global_load_lds((const __attribute__((address_space(1))) void*)g,
                                     (__attribute__((address_space(3))) void*)l, 16, 0, 0);
}

// ---------------------------------------------------------------------------
// fp32 -> bf16 elementwise convert, 8 elems/thread, grid-stride
__global__ __launch_bounds__(256) void cvt_bf16_k(const float* __restrict__ in,
                                                  bf16_t* __restrict__ out, int n8) {
    int idx = blockIdx.x * 256 + threadIdx.x;
    int stride = gridDim.x * 256;
    for (int i = idx; i < n8; i += stride) {
        size_t off = (size_t)i * 8;
        float4 a = *(const float4*)(in + off);
        float4 b = *(const float4*)(in + off + 4);
        bf16x8 o = { (__bf16)a.x, (__bf16)a.y, (__bf16)a.z, (__bf16)a.w,
                     (__bf16)b.x, (__bf16)b.y, (__bf16)b.z, (__bf16)b.w };
        *(bf16x8*)(out + off) = o;
    }
}

// ---------------------------------------------------------------------------
// x (C=8192, N=1024) fp32 -> xT (N, C) bf16, LDS-tiled transpose
__global__ __launch_bounds__(256) void transpose_cvt_x(const float* __restrict__ x,
                                                       bf16_t* __restrict__ xT) {
    __shared__ float t[32][33];
    const int n0 = blockIdx.x * 32, c0 = blockIdx.y * 32;
    const int tx = threadIdx.x, ty = threadIdx.y; // block (32,8)
    #pragma unroll
    for (int i = 0; i < 4; ++i)
        t[ty + i * 8][tx] = x[(size_t)(c0 + ty + i * 8) * NDIM + n0 + tx];
    __syncthreads();
    #pragma unroll
    for (int i = 0; i < 4; ++i)
        xT[(size_t)(n0 + ty + i * 8) * CDIM + c0 + tx] = (__bf16)t[tx][ty + i * 8];
}

// ---------------------------------------------------------------------------
// Mega-GEMM: C[i,j] = sum_k A[i,k]*B[j,k], A = [Wv;Wq;Wk] (M=10240), B = xT.
// 128x128 tile, BK=32, 4 waves, XCD-swizzled grid (640 blocks).
// Double-buffered LDS, ONE barrier per K-step: STAGE(t+1) issued before
// compute(t); prev-iter barrier's vmcnt drain guarantees buf[t] is ready.
// Fused epilogue: v rows -> bf16 with scale/shift; q/k rows -> fp32.
__global__ __launch_bounds__(256) void mega_gemm(
    const bf16_t* __restrict__ Wv, const bf16_t* __restrict__ Wq,
    const bf16_t* __restrict__ Wk, const bf16_t* __restrict__ Bx,
    bf16_t* __restrict__ v_out, float* __restrict__ q_out, float* __restrict__ k_out,
    const float* __restrict__ v_scale, const float* __restrict__ v_shift,
    const float* __restrict__ q_scale, const float* __restrict__ q_shift,
    const float* __restrict__ k_scale, const float* __restrict__ k_shift)
{
    // XCD-aware bijective swizzle (nwg = 640, %8 == 0)
    const int lin = blockIdx.y * 8 + blockIdx.x;
    const int tile = (lin & 7) * 80 + (lin >> 3);
    const int row0 = (tile >> 3) * 128;
    const int col0 = (tile & 7) * 128;

    const bf16_t* A; const float* s0; const float* s1;
    int arow; int path; // 0=v,1=q,2=k
    if (row0 < 8192)      { A = Wv; arow = row0;        s0 = v_scale; s1 = v_shift; path = 0; }
    else if (row0 < 9216) { A = Wq; arow = row0 - 8192; s0 = q_scale; s1 = q_shift; path = 1; }
    else                  { A = Wk; arow = row0 - 9216; s0 = k_scale; s1 = k_shift; path = 2; }

    const int tid = threadIdx.x;
    __shared__ __align__(16) bf16_t As[2 * 4096];
    __shared__ __align__(16) bf16_t Bs[2 * 4096];

    const int lane = tid & 63;
    const int w    = tid >> 6;
    const int wm   = (w >> 1) * 64;
    const int wn   = (w & 1) * 64;
    const int lr   = lane & 15;
    const int kg   = (lane >> 4) * 8;

    f32x4 acc[4][4];
    #pragma unroll
    for (int a_ = 0; a_ < 4; ++a_)
        #pragma unroll
        for (int b_ = 0; b_ < 4; ++b_)
            acc[a_][b_] = (f32x4){0.f, 0.f, 0.f, 0.f};

    const int eA = tid * 8;
    const int eB = (256 + tid) * 8;
    const int rA = eA >> 5, cA = eA & 31;
    const int rB = eB >> 5, cB = eB & 31;

#define MEGA_STAGE(buf, kb)                                                        \
    do {                                                                           \
        gload_lds16(A  + (size_t)(arow + rA) * CDIM + (kb) + cA, As + (buf)*4096 + eA); \
        gload_lds16(A  + (size_t)(arow + rB) * CDIM + (kb) + cB, As + (buf)*4096 + eB); \
        gload_lds16(Bx + (size_t)(col0 + rA) * CDIM + (kb) + cA, Bs + (buf)*4096 + eA); \
        gload_lds16(Bx + (size_t)(col0 + rB) * CDIM + (kb) + cB, Bs + (buf)*4096 + eB); \
    } while (0)

    MEGA_STAGE(0, 0);
    __syncthreads();
    int cur = 0;
    for (int kb = 0; kb < CDIM; kb += 32) {
        if (kb + 32 < CDIM) MEGA_STAGE(cur ^ 1, kb + 32);
        const bf16_t* Ac = As + cur * 4096;
        const bf16_t* Bc = Bs + cur * 4096;

        bf16x8 av[4], bv[4];
        #pragma unroll
        for (int mi = 0; mi < 4; ++mi)
            av[mi] = *(const bf16x8*)(Ac + (wm + mi * 16 + lr) * 32 + kg);
        #pragma unroll
        for (int ni = 0; ni < 4; ++ni)
            bv[ni] = *(const bf16x8*)(Bc + (wn + ni * 16 + lr) * 32 + kg);

        #pragma unroll
        for (int mi = 0; mi < 4; ++mi)
            #pragma unroll
            for (int ni = 0; ni < 4; ++ni)
                acc[mi][ni] = __builtin_amdgcn_mfma_f32_16x16x32_bf16(
                    av[mi], bv[ni], acc[mi][ni], 0, 0, 0);
        __syncthreads();
        cur ^= 1;
    }
#undef MEGA_STAGE

    const int cr = (lane >> 4) * 4;  // C/D: col = lane&15, row = (lane>>4)*4 + r
    #pragma unroll
    for (int mi = 0; mi < 4; ++mi) {
        #pragma unroll
        for (int ni = 0; ni < 4; ++ni) {
            const int j = col0 + wn + ni * 16 + lr;
            #pragma unroll
            for (int r = 0; r < 4; ++r) {
                const int il = arow + wm + mi * 16 + cr + r; // local row in its matrix
                float v = acc[mi][ni][r] * s0[il] + s1[il];
                if (path == 0)      v_out[(size_t)il * NDIM + j] = (__bf16)v;
                else if (path == 1) q_out[(size_t)il * NDIM + j] = v;
                else                k_out[(size_t)il * NDIM + j] = v;
            }
        }
    }
}

// ---------------------------------------------------------------------------
// bt-GEMM: C[i,j] = sum_k A[i,k] * B[j,k]. XCD-swizzled xy grid; optional
// split-K via gridDim.z (each z writes its own partial plane C + z*M*N).
// Double-buffered LDS, one barrier per K-step (same discipline as mega).
// EPI: 2 = v*(1/1023)/(e0[j]*e1[j])  -> ppmcc partial
//      3 = gs[0]*v + e0[i*N+j]       -> gamma*out + x
template <int EPI, typename OutT>
__global__ __launch_bounds__(256) void gemm_bt(
    const bf16_t* __restrict__ A, const bf16_t* __restrict__ B,
    OutT* __restrict__ C, int M, int N, int K,
    const float* __restrict__ e0, const float* __restrict__ e1,
    const float* __restrict__ gs)
{
    const int gx = gridDim.x;
    const int nwg = gx * gridDim.y;
    const int lin = blockIdx.y * gx + blockIdx.x;
    int tile = lin;
    if ((nwg & 7) == 0) tile = (lin & 7) * (nwg >> 3) + (lin >> 3);
    const int row0 = (tile / gx) * 128;
    const int col0 = (tile % gx) * 128;

    const int Ks  = K / gridDim.z;
    const int kb0 = blockIdx.z * Ks;
    const int kb1 = kb0 + Ks;
    OutT* Cz = C + (size_t)blockIdx.z * M * N;

    const int tid = threadIdx.x;
    __shared__ __align__(16) bf16_t As[2 * 4096];
    __shared__ __align__(16) bf16_t Bs[2 * 4096];

    const int lane = tid & 63;
    const int w    = tid >> 6;
    const int wm   = (w >> 1) * 64;
    const int wn   = (w & 1) * 64;
    const int lr   = lane & 15;
    const int kg   = (lane >> 4) * 8;

    f32x4 acc[4][4];
    #pragma unroll
    for (int a_ = 0; a_ < 4; ++a_)
        #pragma unroll
        for (int b_ = 0; b_ < 4; ++b_)
            acc[a_][b_] = (f32x4){0.f, 0.f, 0.f, 0.f};

    const int eA = tid * 8;
    const int eB = (256 + tid) * 8;
    const int rA = eA >> 5, cA = eA & 31;
    const int rB = eB >> 5, cB = eB & 31;

#define BT_STAGE(buf, kb)                                                       \
    do {                                                                        \
        gload_lds16(A + (size_t)(row0 + rA) * K + (kb) + cA, As + (buf)*4096 + eA); \
        gload_lds16(A + (size_t)(row0 + rB) * K + (kb) + cB, As + (buf)*4096 + eB); \
        gload_lds16(B + (size_t)(col0 + rA) * K + (kb) + cA, Bs + (buf)*4096 + eA); \
        gload_lds16(B + (size_t)(col0 + rB) * K + (kb) + cB, Bs + (buf)*4096 + eB); \
    } while (0)

    BT_STAGE(0, kb0);
    __syncthreads();
    int cur = 0;
    for (int kb = kb0; kb < kb1; kb += 32) {
        if (kb + 32 < kb1) BT_STAGE(cur ^ 1, kb + 32);
        const bf16_t* Ac = As + cur * 4096;
        const bf16_t* Bc = Bs + cur * 4096;

        bf16x8 av[4], bv[4];
        #pragma unroll
        for (int mi = 0; mi < 4; ++mi)
            av[mi] = *(const bf16x8*)(Ac + (wm + mi * 16 + lr) * 32 + kg);
        #pragma unroll
        for (int ni = 0; ni < 4; ++ni)
            bv[ni] = *(const bf16x8*)(Bc + (wn + ni * 16 + lr) * 32 + kg);

        #pragma unroll
        for (int mi = 0; mi < 4; ++mi)
            #pragma unroll
            for (int ni = 0; ni < 4; ++ni)
                acc[mi][ni] = __builtin_amdgcn_mfma_f32_16x16x32_bf16(
                    av[mi], bv[ni], acc[mi][ni], 0, 0, 0);
        __syncthreads();
        cur ^= 1;
    }
#undef BT_STAGE

    float g = 0.f;
    if (EPI == 3) g = gs[0];
    const int cr = (lane >> 4) * 4;
    #pragma unroll
    for (int mi = 0; mi < 4; ++mi) {
        #pragma unroll
        for (int ni = 0; ni < 4; ++ni) {
            const int j = col0 + wn + ni * 16 + lr;
            float s0 = 0.f, s1 = 0.f;
            if (EPI == 2) { s0 = e0[j]; s1 = e1[j]; }
            #pragma unroll
            for (int r = 0; r < 4; ++r) {
                const int i = row0 + wm + mi * 16 + cr + r;
                float v = acc[mi][ni][r];
                if (EPI == 2)      v = v * (1.0f / 1023.0f) / (s0 * s1);
                else if (EPI == 3) v = g * v + e0[(size_t)i * N + j];
                Cz[(size_t)i * N + j] = (OutT)v;
            }
        }
    }
}

// ---------------------------------------------------------------------------
// Row mean/std (ddof=0) of q_on / k_on (each 1024 x 1024 fp32). One wave/row.
__global__ __launch_bounds__(256) void rowstats(
    const float* __restrict__ Q, const float* __restrict__ Km,
    float* __restrict__ qmean, float* __restrict__ qstd,
    float* __restrict__ kmean, float* __restrict__ kstd)
{
    const int wid  = blockIdx.x * 4 + (threadIdx.x >> 6);
    const int lane = threadIdx.x & 63;
    const float* src = (wid < 1024) ? (Q + (size_t)wid * NDIM)
                                    : (Km + (size_t)(wid - 1024) * NDIM);
    float s = 0.f, s2 = 0.f;
    #pragma unroll
    for (int p = 0; p < 4; ++p) {
        float4 v = *(const float4*)(src + p * 256 + lane * 4);
        s  += v.x + v.y + v.z + v.w;
        s2 += v.x * v.x + v.y * v.y + v.z * v.z + v.w * v.w;
    }
    #pragma unroll
    for (int o = 32; o; o >>= 1) { s += __shfl_xor(s, o); s2 += __shfl_xor(s2, o); }
    if (lane == 0) {
        float m   = s / 1024.f;
        float var = fmaxf(s2 / 1024.f - m * m, 0.f);
        if (wid < 1024) { qmean[wid] = m; qstd[wid] = sqrtf(var); }
        else            { kmean[wid - 1024] = m; kstd[wid - 1024] = sqrtf(var); }
    }
}

// ---------------------------------------------------------------------------
// Center by row mean, transpose (o,n)->(n,o), convert bf16. z selects q/k.
__global__ __launch_bounds__(256) void center_tr(
    const float* __restrict__ Q, const float* __restrict__ qmu, bf16_t* __restrict__ qc,
    const float* __restrict__ Km, const float* __restrict__ kmu, bf16_t* __restrict__ kc)
{
    __shared__ float t[32][33];
    const float* M  = blockIdx.z ? Km  : Q;
    const float* mu = blockIdx.z ? kmu : qmu;
    bf16_t* O       = blockIdx.z ? kc  : qc;
    const int o0 = blockIdx.y * 32, n0 = blockIdx.x * 32;
    const int tx = threadIdx.x, ty = threadIdx.y; // block (32,8)
    #pragma unroll
    for (int i = 0; i < 4; ++i) {
        const int o = o0 + ty + i * 8;
        t[ty + i * 8][tx] = M[(size_t)o * NDIM + n0 + tx] - mu[o];
    }
    __syncthreads();
    #pragma unroll
    for (int i = 0; i < 4; ++i)
        O[(size_t)(n0 + ty + i * 8) * C8D + o0 + tx] = (__bf16)t[tx][ty + i * 8];
}

// ---------------------------------------------------------------------------
// Row softmax over the sum of 4 split-K partial P planes -> bf16 A0.
__global__ __launch_bounds__(256) void softmax_rows(const float* __restrict__ P,
                                                    bf16_t* __restrict__ O) {
    const int row = blockIdx.x;
    const int tid = threadIdx.x;
    const size_t PL = (size_t)NDIM * NDIM / 4;   // plane size in float4 units
    const size_t u  = (size_t)row * (NDIM / 4) + tid;
    const float4* B = (const float4*)P;
    float4 p0 = B[u], p1 = B[u + PL], p2 = B[u + 2 * PL], p3 = B[u + 3 * PL];
    float4 v = { p0.x + p1.x + p2.x + p3.x, p0.y + p1.y + p2.y + p3.y,
                 p0.z + p1.z + p2.z + p3.z, p0.w + p1.w + p2.w + p3.w };
    float mx = fmaxf(fmaxf(v.x, v.y), fmaxf(v.z, v.w));
    #pragma unroll
    for (int o = 32; o; o >>= 1) mx = fmaxf(mx, __shfl_xor(mx, o));
    __shared__ float red[8];
    const int w = tid >> 6, lane = tid & 63;
    if (lane == 0) red[w] = mx;
    __syncthreads();
    mx = fmaxf(fmaxf(red[0], red[1]), fmaxf(red[2], red[3]));
    float e0 = __expf(v.x - mx), e1 = __expf(v.y - mx);
    float e2 = __expf(v.z - mx), e3 = __expf(v.w - mx);
    float s = e0 + e1 + e2 + e3;
    #pragma unroll
    for (int o = 32; o; o >>= 1) s += __shfl_xor(s, o);
    if (lane == 0) red[4 + w] = s;
    __syncthreads();
    s = red[4] + red[5] + red[6] + red[7];
    const float inv = 1.0f / s;
    bf16x4 o4 = { (__bf16)(e0 * inv), (__bf16)(e1 * inv),
                  (__bf16)(e2 * inv), (__bf16)(e3 * inv) };
    ((bf16x4*)(O + (size_t)row * NDIM))[tid] = o4;
}

// ---------------------------------------------------------------------------
extern "C" void kernel_launch(void* const* d_in, const int* in_sizes, int n_in,
                              void* d_out, int out_size, void* d_ws, size_t ws_size,
                              hipStream_t stream)
{
    const float* x       = (const float*)d_in[0];
    const float* Wq      = (const float*)d_in[1];
    const float* Wk      = (const float*)d_in[2];
    const float* Wv      = (const float*)d_in[3];
    const float* q_scale = (const float*)d_in[4];
    const float* q_shift = (const float*)d_in[5];
    const float* k_scale = (const float*)d_in[6];
    const float* k_shift = (const float*)d_in[7];
    const float* v_scale = (const float*)d_in[8];
    const float* v_shift = (const float*)d_in[9];
    const float* gamma   = (const float*)d_in[10];
    float* out = (float*)d_out;

    // workspace layout (~230 MB)
    char* w = (char*)d_ws;
    bf16_t* Wv_b = (bf16_t*)w; w += (size_t)CDIM * CDIM * 2;
    bf16_t* Wq_b = (bf16_t*)w; w += (size_t)C8D  * CDIM * 2;
    bf16_t* Wk_b = (bf16_t*)w; w += (size_t)C8D  * CDIM * 2;
    bf16_t* xT   = (bf16_t*)w; w += (size_t)NDIM * CDIM * 2;
    bf16_t* v_b  = (bf16_t*)w; w += (size_t)CDIM * NDIM * 2;
    float*  q_on = (float*) w; w += (size_t)C8D * NDIM * 4;
    float*  k_on = (float*) w; w += (size_t)C8D * NDIM * 4;
    float*  P    = (float*) w; w += (size_t)4 * NDIM * NDIM * 4;  // 4 split-K planes
    bf16_t* qc   = (bf16_t*)w; w += (size_t)NDIM * C8D * 2;
    bf16_t* kc   = (bf16_t*)w; w += (size_t)NDIM * C8D * 2;
    bf16_t* A0   = (bf16_t*)w; w += (size_t)NDIM * NDIM * 2;
    float*  qmean = (float*)w; w += C8D * 4;
    float*  qstd  = (float*)w; w += C8D * 4;
    float*  kmean = (float*)w; w += C8D * 4;
    float*  kstd  = (float*)w; w += C8D * 4;

    // 1. converts
    cvt_bf16_k<<<2048, 256, 0, stream>>>(Wv, Wv_b, (int)((size_t)CDIM * CDIM / 8));
    cvt_bf16_k<<<2048, 256, 0, stream>>>(Wq, Wq_b, C8D * CDIM / 8);
    cvt_bf16_k<<<2048, 256, 0, stream>>>(Wk, Wk_b, C8D * CDIM / 8);
    transpose_cvt_x<<<dim3(NDIM / 32, CDIM / 32), dim3(32, 8), 0, stream>>>(x, xT);

    // 2. mega-GEMM (640 blocks, fused epilogue, dbuf single-barrier loop)
    mega_gemm<<<dim3(8, MSTACK / 128), 256, 0, stream>>>(
        Wv_b, Wq_b, Wk_b, xT, v_b, q_on, k_on,
        v_scale, v_shift, q_scale, q_shift, k_scale, k_shift);

    // 3. row stats of q_on / k_on (2048 waves)
    rowstats<<<512, 256, 0, stream>>>(q_on, k_on, qmean, qstd, kmean, kstd);

    // 4. center + transpose + bf16
    center_tr<<<dim3(32, 32, 2), dim3(32, 8), 0, stream>>>(
        q_on, qmean, qc, k_on, kmean, kc);

    // 5. P[z] = (qc . kc^T)_z / 1023 / (qstd[j] * kstd[j]), split-K x4 (256 blocks)
    gemm_bt<2, float><<<dim3(NDIM / 128, NDIM / 128, 4), 256, 0, stream>>>(
        qc, kc, P, NDIM, NDIM, C8D, qstd, kstd, nullptr);

    // 6. row softmax over summed partials -> A0 (bf16)
    softmax_rows<<<NDIM, 256, 0, stream>>>(P, A0);

    // 7. out = gamma * (v . A0^T) + x
    gemm_bt<3, float><<<dim3(NDIM / 128, CDIM / 128, 1), 256, 0, stream>>>(
        v_b, A0, out, CDIM, NDIM, NDIM, x, x, gamma);
}

// Round 5
// 416.364 us; speedup vs baseline: 1.2434x; 1.0059x over previous
//
#include <hip/hip_runtime.h>
#include <cstdint>
#include <cstddef>

// Problem dims (fixed)
#define CDIM 8192
#define NDIM 1024   // H*W
#define C8D  1024
#define MSTACK 10240  // 8192 (v) + 1024 (q) + 1024 (k)
#define NT8 128       // K-tiles of 64 in mega GEMM

typedef __bf16 bf16_t;
typedef __bf16 bf16x8 __attribute__((ext_vector_type(8)));
typedef __bf16 bf16x4 __attribute__((ext_vector_type(4)));
typedef float  f32x4  __attribute__((ext_vector_type(4)));

__device__ __forceinline__ void gload_lds16(const void* g, void* l) {
    __builtin_amdgcn_global_load_lds((const __attribute__((address_space(1))) void*)g,
                                     (__attribute__((address_space(3))) void*)l, 16, 0, 0);
}

// ---------------------------------------------------------------------------
// fp32 -> bf16 elementwise convert, 8 elems/thread, grid-stride
__global__ __launch_bounds__(256) void cvt_bf16_k(const float* __restrict__ in,
                                                  bf16_t* __restrict__ out, int n8) {
    int idx = blockIdx.x * 256 + threadIdx.x;
    int stride = gridDim.x * 256;
    for (int i = idx; i < n8; i += stride) {
        size_t off = (size_t)i * 8;
        float4 a = *(const float4*)(in + off);
        float4 b = *(const float4*)(in + off + 4);
        bf16x8 o = { (__bf16)a.x, (__bf16)a.y, (__bf16)a.z, (__bf16)a.w,
                     (__bf16)b.x, (__bf16)b.y, (__bf16)b.z, (__bf16)b.w };
        *(bf16x8*)(out + off) = o;
    }
}

// ---------------------------------------------------------------------------
// x (C=8192, N=1024) fp32 -> xT (N, C) bf16, LDS-tiled transpose
__global__ __launch_bounds__(256) void transpose_cvt_x(const float* __restrict__ x,
                                                       bf16_t* __restrict__ xT) {
    __shared__ float t[32][33];
    const int n0 = blockIdx.x * 32, c0 = blockIdx.y * 32;
    const int tx = threadIdx.x, ty = threadIdx.y; // block (32,8)
    #pragma unroll
    for (int i = 0; i < 4; ++i)
        t[ty + i * 8][tx] = x[(size_t)(c0 + ty + i * 8) * NDIM + n0 + tx];
    __syncthreads();
    #pragma unroll
    for (int i = 0; i < 4; ++i)
        xT[(size_t)(n0 + ty + i * 8) * CDIM + c0 + tx] = (__bf16)t[tx][ty + i * 8];
}

// ---------------------------------------------------------------------------
// Mega-GEMM, 256x256 tile, BK=64, 8 waves (2Mx4N), counted-vmcnt pipeline.
// C[i,j] = sum_k A[i,k]*B[j,k], A = [Wv;Wq;Wk] (M=10240), B = xT (1024x8192).
// LDS 128 KiB: A/B tiles 256x64 bf16, double-buffered. Per K-tile:
//   P1: ds_read frags kk=0 (12 x b128) -> 32 MFMA (setprio-wrapped)
//   P2: same for kk=1
//   lgkmcnt(0); BARRIER_A            (all waves done READING buf b)
//   STAGE(buf b <- tile t+2)         (8 x global_load_lds, linear dest)
//   vmcnt(8)                         (tile t+1's loads landed; t+2's in flight)
//   BARRIER_B                        (buf b^1 ready for everyone)
// Bank-conflict fix (G4): LDS holds col (c ^ ((row&7)<<3)) at linear (row,c):
// achieved by pre-swizzling the GLOBAL source column; reads XOR the same mask.
__global__ __launch_bounds__(512, 2) void mega_gemm8(
    const bf16_t* __restrict__ Wv, const bf16_t* __restrict__ Wq,
    const bf16_t* __restrict__ Wk, const bf16_t* __restrict__ Bx,
    bf16_t* __restrict__ v_out, float* __restrict__ q_out, float* __restrict__ k_out,
    const float* __restrict__ v_scale, const float* __restrict__ v_shift,
    const float* __restrict__ q_scale, const float* __restrict__ q_shift,
    const float* __restrict__ k_scale, const float* __restrict__ k_shift)
{
    __shared__ __align__(16) bf16_t Ld[65536];   // 128 KiB: A[2][16384], B[2][16384]

    const int tid  = threadIdx.x;
    const int lane = tid & 63;
    const int wid  = tid >> 6;
    const int wr   = wid >> 2;        // 0..1  (M half)
    const int wc   = wid & 3;         // 0..3  (N quarter)

    // XCD-aware bijective swizzle (nwg = 160, %8 == 0; 20 tiles per XCD)
    const int lin  = blockIdx.y * 4 + blockIdx.x;
    const int tile = (lin & 7) * 20 + (lin >> 3);
    const int trow = tile >> 2;
    const int col0 = (tile & 3) * 256;

    const bf16_t* Ag; const float* s0; const float* s1; int arow, path;
    if (trow < 32)      { Ag = Wv; arow = trow * 256;        s0 = v_scale; s1 = v_shift; path = 0; }
    else if (trow < 36) { Ag = Wq; arow = trow * 256 - 8192; s0 = q_scale; s1 = q_shift; path = 1; }
    else                { Ag = Wk; arow = trow * 256 - 9216; s0 = k_scale; s1 = k_shift; path = 2; }

    // staging geometry: issue i covers rows [i*64, i*64+64); thread -> (row, colblk)
    const int ar0 = tid >> 3;                                  // base row (0..63)
    const int o0  = tid * 8;                                   // LDS elem offset
    const int csw = (((tid & 7) ^ ((tid >> 3) & 7)) << 3);     // pre-swizzled src col

    // read geometry (elem offsets into Ld)
    const int aRow = (wr * 128 + (lane & 15)) * 64;            // A frag row base
    const int bRow = 32768 + (wc * 64 + (lane & 15)) * 64;     // B frag row base
    const int ac0  = (((lane >> 4) * 8)     ) ^ ((lane & 7) << 3);  // kk=0 col
    const int ac1  = (32 + ((lane >> 4) * 8)) ^ ((lane & 7) << 3);  // kk=1 col

    f32x4 acc[8][4];
    #pragma unroll
    for (int mi = 0; mi < 8; ++mi)
        #pragma unroll
        for (int ni = 0; ni < 4; ++ni)
            acc[mi][ni] = (f32x4){0.f, 0.f, 0.f, 0.f};

#define STAGE8(BUF, KB) do {                                                                  \
    gload_lds16(Ag + (size_t)(arow + ar0      ) * CDIM + (KB) + csw, Ld + (BUF)*16384 + o0          ); \
    gload_lds16(Ag + (size_t)(arow + ar0 +  64) * CDIM + (KB) + csw, Ld + (BUF)*16384 + o0 +  4096  ); \
    gload_lds16(Ag + (size_t)(arow + ar0 + 128) * CDIM + (KB) + csw, Ld + (BUF)*16384 + o0 +  8192  ); \
    gload_lds16(Ag + (size_t)(arow + ar0 + 192) * CDIM + (KB) + csw, Ld + (BUF)*16384 + o0 + 12288  ); \
    gload_lds16(Bx + (size_t)(col0 + ar0      ) * CDIM + (KB) + csw, Ld + 32768 + (BUF)*16384 + o0          ); \
    gload_lds16(Bx + (size_t)(col0 + ar0 +  64) * CDIM + (KB) + csw, Ld + 32768 + (BUF)*16384 + o0 +  4096  ); \
    gload_lds16(Bx + (size_t)(col0 + ar0 + 128) * CDIM + (KB) + csw, Ld + 32768 + (BUF)*16384 + o0 +  8192  ); \
    gload_lds16(Bx + (size_t)(col0 + ar0 + 192) * CDIM + (KB) + csw, Ld + 32768 + (BUF)*16384 + o0 + 12288  ); \
} while (0)

#define HALF_MMA(BUF, AC) do {                                                                \
    bf16x8 av[8], bv[4];                                                                      \
    _Pragma("unroll") for (int mi = 0; mi < 8; ++mi)                                          \
        av[mi] = *(const bf16x8*)(Ld + (BUF)*16384 + aRow + mi*1024 + (AC));                  \
    _Pragma("unroll") for (int ni = 0; ni < 4; ++ni)                                          \
        bv[ni] = *(const bf16x8*)(Ld + (BUF)*16384 + bRow + ni*1024 + (AC));                  \
    __builtin_amdgcn_s_setprio(1);                                                            \
    _Pragma("unroll") for (int mi = 0; mi < 8; ++mi)                                          \
        _Pragma("unroll") for (int ni = 0; ni < 4; ++ni)                                      \
            acc[mi][ni] = __builtin_amdgcn_mfma_f32_16x16x32_bf16(av[mi], bv[ni],             \
                                                                  acc[mi][ni], 0, 0, 0);      \
    __builtin_amdgcn_s_setprio(0);                                                            \
} while (0)

#define TILE8(BUF, T) do {                                                                    \
    HALF_MMA(BUF, ac0);                                                                       \
    HALF_MMA(BUF, ac1);                                                                       \
    if ((T) != NT8 - 1) {                                                                     \
        asm volatile("s_waitcnt lgkmcnt(0)" ::: "memory");                                    \
        __builtin_amdgcn_sched_barrier(0);                                                    \
        __builtin_amdgcn_s_barrier();                 /* BARRIER_A: reads of buf done */      \
        __builtin_amdgcn_sched_barrier(0);                                                    \
        if ((T) + 2 < NT8) {                                                                  \
            STAGE8(BUF, ((T) + 2) * 64);                                                      \
            asm volatile("s_waitcnt vmcnt(8)" ::: "memory");                                  \
        } else {                                                                              \
            asm volatile("s_waitcnt vmcnt(0)" ::: "memory");                                  \
        }                                                                                     \
        __builtin_amdgcn_sched_barrier(0);                                                    \
        __builtin_amdgcn_s_barrier();                 /* BARRIER_B: next buf ready */         \
        __builtin_amdgcn_sched_barrier(0);                                                    \
    }                                                                                         \
} while (0)

    // prologue: stage tiles 0 and 1; drain tile 0 (leave tile 1 in flight)
    STAGE8(0, 0);
    STAGE8(1, 64);
    asm volatile("s_waitcnt vmcnt(8)" ::: "memory");
    __builtin_amdgcn_sched_barrier(0);
    __builtin_amdgcn_s_barrier();
    __builtin_amdgcn_sched_barrier(0);

    for (int t = 0; t < NT8; t += 2) {
        TILE8(0, t);
        TILE8(1, t + 1);
    }
#undef TILE8
#undef HALF_MMA
#undef STAGE8

    // epilogue: C/D layout col = lane&15, row = (lane>>4)*4 + r
    const int cq = (lane >> 4) * 4;
    #pragma unroll
    for (int mi = 0; mi < 8; ++mi) {
        #pragma unroll
        for (int ni = 0; ni < 4; ++ni) {
            const int j = col0 + wc * 64 + ni * 16 + (lane & 15);
            #pragma unroll
            for (int r = 0; r < 4; ++r) {
                const int il = arow + wr * 128 + mi * 16 + cq + r;  // row in its matrix
                float vv = acc[mi][ni][r] * s0[il] + s1[il];
                if (path == 0)      v_out[(size_t)il * NDIM + j] = (__bf16)vv;
                else if (path == 1) q_out[(size_t)il * NDIM + j] = vv;
                else                k_out[(size_t)il * NDIM + j] = vv;
            }
        }
    }
}

// ---------------------------------------------------------------------------
// bt-GEMM: C[i,j] = sum_k A[i,k] * B[j,k]. XCD-swizzled xy grid; optional
// split-K via gridDim.z (each z writes its own partial plane C + z*M*N).
// EPI: 2 = v*(1/1023)/(e0[j]*e1[j])  -> ppmcc partial
//      3 = gs[0]*v + e0[i*N+j]       -> gamma*out + x
template <int EPI, typename OutT>
__global__ __launch_bounds__(256) void gemm_bt(
    const bf16_t* __restrict__ A, const bf16_t* __restrict__ B,
    OutT* __restrict__ C, int M, int N, int K,
    const float* __restrict__ e0, const float* __restrict__ e1,
    const float* __restrict__ gs)
{
    const int gx = gridDim.x;
    const int nwg = gx * gridDim.y;
    const int lin = blockIdx.y * gx + blockIdx.x;
    int tile = lin;
    if ((nwg & 7) == 0) tile = (lin & 7) * (nwg >> 3) + (lin >> 3);
    const int row0 = (tile / gx) * 128;
    const int col0 = (tile % gx) * 128;

    const int Ks  = K / gridDim.z;
    const int kb0 = blockIdx.z * Ks;
    const int kb1 = kb0 + Ks;
    OutT* Cz = C + (size_t)blockIdx.z * M * N;

    const int tid = threadIdx.x;
    __shared__ __align__(16) bf16_t As[2 * 4096];
    __shared__ __align__(16) bf16_t Bs[2 * 4096];

    const int lane = tid & 63;
    const int w    = tid >> 6;
    const int wm   = (w >> 1) * 64;
    const int wn   = (w & 1) * 64;
    const int lr   = lane & 15;
    const int kg   = (lane >> 4) * 8;

    f32x4 acc[4][4];
    #pragma unroll
    for (int a_ = 0; a_ < 4; ++a_)
        #pragma unroll
        for (int b_ = 0; b_ < 4; ++b_)
            acc[a_][b_] = (f32x4){0.f, 0.f, 0.f, 0.f};

    const int eA = tid * 8;
    const int eB = (256 + tid) * 8;
    const int rA = eA >> 5, cA = eA & 31;
    const int rB = eB >> 5, cB = eB & 31;

#define BT_STAGE(buf, kb)                                                       \
    do {                                                                        \
        gload_lds16(A + (size_t)(row0 + rA) * K + (kb) + cA, As + (buf)*4096 + eA); \
        gload_lds16(A + (size_t)(row0 + rB) * K + (kb) + cB, As + (buf)*4096 + eB); \
        gload_lds16(B + (size_t)(col0 + rA) * K + (kb) + cA, Bs + (buf)*4096 + eA); \
        gload_lds16(B + (size_t)(col0 + rB) * K + (kb) + cB, Bs + (buf)*4096 + eB); \
    } while (0)

    BT_STAGE(0, kb0);
    __syncthreads();
    int cur = 0;
    for (int kb = kb0; kb < kb1; kb += 32) {
        if (kb + 32 < kb1) BT_STAGE(cur ^ 1, kb + 32);
        const bf16_t* Ac = As + cur * 4096;
        const bf16_t* Bc = Bs + cur * 4096;

        bf16x8 av[4], bv[4];
        #pragma unroll
        for (int mi = 0; mi < 4; ++mi)
            av[mi] = *(const bf16x8*)(Ac + (wm + mi * 16 + lr) * 32 + kg);
        #pragma unroll
        for (int ni = 0; ni < 4; ++ni)
            bv[ni] = *(const bf16x8*)(Bc + (wn + ni * 16 + lr) * 32 + kg);

        #pragma unroll
        for (int mi = 0; mi < 4; ++mi)
            #pragma unroll
            for (int ni = 0; ni < 4; ++ni)
                acc[mi][ni] = __builtin_amdgcn_mfma_f32_16x16x32_bf16(
                    av[mi], bv[ni], acc[mi][ni], 0, 0, 0);
        __syncthreads();
        cur ^= 1;
    }
#undef BT_STAGE

    float g = 0.f;
    if (EPI == 3) g = gs[0];
    const int cr = (lane >> 4) * 4;
    #pragma unroll
    for (int mi = 0; mi < 4; ++mi) {
        #pragma unroll
        for (int ni = 0; ni < 4; ++ni) {
            const int j = col0 + wn + ni * 16 + lr;
            float s0 = 0.f, s1 = 0.f;
            if (EPI == 2) { s0 = e0[j]; s1 = e1[j]; }
            #pragma unroll
            for (int r = 0; r < 4; ++r) {
                const int i = row0 + wm + mi * 16 + cr + r;
                float v = acc[mi][ni][r];
                if (EPI == 2)      v = v * (1.0f / 1023.0f) / (s0 * s1);
                else if (EPI == 3) v = g * v + e0[(size_t)i * N + j];
                Cz[(size_t)i * N + j] = (OutT)v;
            }
        }
    }
}

// ---------------------------------------------------------------------------
// Row mean/std (ddof=0) of q_on / k_on (each 1024 x 1024 fp32). One wave/row.
__global__ __launch_bounds__(256) void rowstats(
    const float* __restrict__ Q, const float* __restrict__ Km,
    float* __restrict__ qmean, float* __restrict__ qstd,
    float* __restrict__ kmean, float* __restrict__ kstd)
{
    const int wid  = blockIdx.x * 4 + (threadIdx.x >> 6);
    const int lane = threadIdx.x & 63;
    const float* src = (wid < 1024) ? (Q + (size_t)wid * NDIM)
                                    : (Km + (size_t)(wid - 1024) * NDIM);
    float s = 0.f, s2 = 0.f;
    #pragma unroll
    for (int p = 0; p < 4; ++p) {
        float4 v = *(const float4*)(src + p * 256 + lane * 4);
        s  += v.x + v.y + v.z + v.w;
        s2 += v.x * v.x + v.y * v.y + v.z * v.z + v.w * v.w;
    }
    #pragma unroll
    for (int o = 32; o; o >>= 1) { s += __shfl_xor(s, o); s2 += __shfl_xor(s2, o); }
    if (lane == 0) {
        float m   = s / 1024.f;
        float var = fmaxf(s2 / 1024.f - m * m, 0.f);
        if (wid < 1024) { qmean[wid] = m; qstd[wid] = sqrtf(var); }
        else            { kmean[wid - 1024] = m; kstd[wid - 1024] = sqrtf(var); }
    }
}

// ---------------------------------------------------------------------------
// Center by row mean, transpose (o,n)->(n,o), convert bf16. z selects q/k.
__global__ __launch_bounds__(256) void center_tr(
    const float* __restrict__ Q, const float* __restrict__ qmu, bf16_t* __restrict__ qc,
    const float* __restrict__ Km, const float* __restrict__ kmu, bf16_t* __restrict__ kc)
{
    __shared__ float t[32][33];
    const float* M  = blockIdx.z ? Km  : Q;
    const float* mu = blockIdx.z ? kmu : qmu;
    bf16_t* O       = blockIdx.z ? kc  : qc;
    const int o0 = blockIdx.y * 32, n0 = blockIdx.x * 32;
    const int tx = threadIdx.x, ty = threadIdx.y; // block (32,8)
    #pragma unroll
    for (int i = 0; i < 4; ++i) {
        const int o = o0 + ty + i * 8;
        t[ty + i * 8][tx] = M[(size_t)o * NDIM + n0 + tx] - mu[o];
    }
    __syncthreads();
    #pragma unroll
    for (int i = 0; i < 4; ++i)
        O[(size_t)(n0 + ty + i * 8) * C8D + o0 + tx] = (__bf16)t[tx][ty + i * 8];
}

// ---------------------------------------------------------------------------
// Row softmax over the sum of 4 split-K partial P planes -> bf16 A0.
__global__ __launch_bounds__(256) void softmax_rows(const float* __restrict__ P,
                                                    bf16_t* __restrict__ O) {
    const int row = blockIdx.x;
    const int tid = threadIdx.x;
    const size_t PL = (size_t)NDIM * NDIM / 4;   // plane size in float4 units
    const size_t u  = (size_t)row * (NDIM / 4) + tid;
    const float4* B = (const float4*)P;
    float4 p0 = B[u], p1 = B[u + PL], p2 = B[u + 2 * PL], p3 = B[u + 3 * PL];
    float4 v = { p0.x + p1.x + p2.x + p3.x, p0.y + p1.y + p2.y + p3.y,
                 p0.z + p1.z + p2.z + p3.z, p0.w + p1.w + p2.w + p3.w };
    float mx = fmaxf(fmaxf(v.x, v.y), fmaxf(v.z, v.w));
    #pragma unroll
    for (int o = 32; o; o >>= 1) mx = fmaxf(mx, __shfl_xor(mx, o));
    __shared__ float red[8];
    const int w = tid >> 6, lane = tid & 63;
    if (lane == 0) red[w] = mx;
    __syncthreads();
    mx = fmaxf(fmaxf(red[0], red[1]), fmaxf(red[2], red[3]));
    float e0 = __expf(v.x - mx), e1 = __expf(v.y - mx);
    float e2 = __expf(v.z - mx), e3 = __expf(v.w - mx);
    float s = e0 + e1 + e2 + e3;
    #pragma unroll
    for (int o = 32; o; o >>= 1) s += __shfl_xor(s, o);
    if (lane == 0) red[4 + w] = s;
    __syncthreads();
    s = red[4] + red[5] + red[6] + red[7];
    const float inv = 1.0f / s;
    bf16x4 o4 = { (__bf16)(e0 * inv), (__bf16)(e1 * inv),
                  (__bf16)(e2 * inv), (__bf16)(e3 * inv) };
    ((bf16x4*)(O + (size_t)row * NDIM))[tid] = o4;
}

// ---------------------------------------------------------------------------
extern "C" void kernel_launch(void* const* d_in, const int* in_sizes, int n_in,
                              void* d_out, int out_size, void* d_ws, size_t ws_size,
                              hipStream_t stream)
{
    const float* x       = (const float*)d_in[0];
    const float* Wq      = (const float*)d_in[1];
    const float* Wk      = (const float*)d_in[2];
    const float* Wv      = (const float*)d_in[3];
    const float* q_scale = (const float*)d_in[4];
    const float* q_shift = (const float*)d_in[5];
    const float* k_scale = (const float*)d_in[6];
    const float* k_shift = (const float*)d_in[7];
    const float* v_scale = (const float*)d_in[8];
    const float* v_shift = (const float*)d_in[9];
    const float* gamma   = (const float*)d_in[10];
    float* out = (float*)d_out;

    // workspace layout (~230 MB)
    char* w = (char*)d_ws;
    bf16_t* Wv_b = (bf16_t*)w; w += (size_t)CDIM * CDIM * 2;
    bf16_t* Wq_b = (bf16_t*)w; w += (size_t)C8D  * CDIM * 2;
    bf16_t* Wk_b = (bf16_t*)w; w += (size_t)C8D  * CDIM * 2;
    bf16_t* xT   = (bf16_t*)w; w += (size_t)NDIM * CDIM * 2;
    bf16_t* v_b  = (bf16_t*)w; w += (size_t)CDIM * NDIM * 2;
    float*  q_on = (float*) w; w += (size_t)C8D * NDIM * 4;
    float*  k_on = (float*) w; w += (size_t)C8D * NDIM * 4;
    float*  P    = (float*) w; w += (size_t)4 * NDIM * NDIM * 4;  // 4 split-K planes
    bf16_t* qc   = (bf16_t*)w; w += (size_t)NDIM * C8D * 2;
    bf16_t* kc   = (bf16_t*)w; w += (size_t)NDIM * C8D * 2;
    bf16_t* A0   = (bf16_t*)w; w += (size_t)NDIM * NDIM * 2;
    float*  qmean = (float*)w; w += C8D * 4;
    float*  qstd  = (float*)w; w += C8D * 4;
    float*  kmean = (float*)w; w += C8D * 4;
    float*  kstd  = (float*)w; w += C8D * 4;

    // 1. converts
    cvt_bf16_k<<<2048, 256, 0, stream>>>(Wv, Wv_b, (int)((size_t)CDIM * CDIM / 8));
    cvt_bf16_k<<<2048, 256, 0, stream>>>(Wq, Wq_b, C8D * CDIM / 8);
    cvt_bf16_k<<<2048, 256, 0, stream>>>(Wk, Wk_b, C8D * CDIM / 8);
    transpose_cvt_x<<<dim3(NDIM / 32, CDIM / 32), dim3(32, 8), 0, stream>>>(x, xT);

    // 2. mega-GEMM, 256^2 counted-vmcnt pipeline (160 blocks x 512 thr)
    mega_gemm8<<<dim3(4, MSTACK / 256), 512, 0, stream>>>(
        Wv_b, Wq_b, Wk_b, xT, v_b, q_on, k_on,
        v_scale, v_shift, q_scale, q_shift, k_scale, k_shift);

    // 3. row stats of q_on / k_on (2048 waves)
    rowstats<<<512, 256, 0, stream>>>(q_on, k_on, qmean, qstd, kmean, kstd);

    // 4. center + transpose + bf16
    center_tr<<<dim3(32, 32, 2), dim3(32, 8), 0, stream>>>(
        q_on, qmean, qc, k_on, kmean, kc);

    // 5. P[z] = (qc . kc^T)_z / 1023 / (qstd[j] * kstd[j]), split-K x4 (256 blocks)
    gemm_bt<2, float><<<dim3(NDIM / 128, NDIM / 128, 4), 256, 0, stream>>>(
        qc, kc, P, NDIM, NDIM, C8D, qstd, kstd, nullptr);

    // 6. row softmax over summed partials -> A0 (bf16)
    softmax_rows<<<NDIM, 256, 0, stream>>>(P, A0);

    // 7. out = gamma * (v . A0^T) + x
    gemm_bt<3, float><<<dim3(NDIM / 128, CDIM / 128, 1), 256, 0, stream>>>(
        v_b, A0, out, CDIM, NDIM, NDIM, x, x, gamma);
}

// Round 6
// 355.309 us; speedup vs baseline: 1.4571x; 1.1718x over previous
//
#include <hip/hip_runtime.h>
#include <cstdint>
#include <cstddef>

// Problem dims (fixed)
#define CDIM 8192
#define NDIM 1024   // H*W
#define C8D  1024
#define MSTACK 10240  // 8192 (v) + 1024 (q) + 1024 (k)
#define NT8 128       // K-tiles of 64 in mega GEMM

typedef __bf16 bf16_t;
typedef __bf16 bf16x8 __attribute__((ext_vector_type(8)));
typedef __bf16 bf16x4 __attribute__((ext_vector_type(4)));
typedef float  f32x4  __attribute__((ext_vector_type(4)));

__device__ __forceinline__ void gload_lds16(const void* g, void* l) {
    __builtin_amdgcn_global_load_lds((const __attribute__((address_space(1))) void*)g,
                                     (__attribute__((address_space(3))) void*)l, 16, 0, 0);
}

// ---------------------------------------------------------------------------
// fp32 -> bf16 elementwise convert, 8 elems/thread, grid-stride
__global__ __launch_bounds__(256) void cvt_bf16_k(const float* __restrict__ in,
                                                  bf16_t* __restrict__ out, int n8) {
    int idx = blockIdx.x * 256 + threadIdx.x;
    int stride = gridDim.x * 256;
    for (int i = idx; i < n8; i += stride) {
        size_t off = (size_t)i * 8;
        float4 a = *(const float4*)(in + off);
        float4 b = *(const float4*)(in + off + 4);
        bf16x8 o = { (__bf16)a.x, (__bf16)a.y, (__bf16)a.z, (__bf16)a.w,
                     (__bf16)b.x, (__bf16)b.y, (__bf16)b.z, (__bf16)b.w };
        *(bf16x8*)(out + off) = o;
    }
}

// ---------------------------------------------------------------------------
// x (C=8192, N=1024) fp32 -> xT (N, C) bf16, LDS-tiled transpose
__global__ __launch_bounds__(256) void transpose_cvt_x(const float* __restrict__ x,
                                                       bf16_t* __restrict__ xT) {
    __shared__ float t[32][33];
    const int n0 = blockIdx.x * 32, c0 = blockIdx.y * 32;
    const int tx = threadIdx.x, ty = threadIdx.y; // block (32,8)
    #pragma unroll
    for (int i = 0; i < 4; ++i)
        t[ty + i * 8][tx] = x[(size_t)(c0 + ty + i * 8) * NDIM + n0 + tx];
    __syncthreads();
    #pragma unroll
    for (int i = 0; i < 4; ++i)
        xT[(size_t)(n0 + ty + i * 8) * CDIM + c0 + tx] = (__bf16)t[tx][ty + i * 8];
}

// ---------------------------------------------------------------------------
// Mega-GEMM, 256x256 tile, BK=64, 8 waves (2Mx4N), m201-style 4-phase/K-tile
// schedule. C[i,j] = sum_k A[i,k]*B[j,k], A=[Wv;Wq;Wk] (M=10240), B=xT.
// Per K-tile t (slot d=t&1), phases = C-quadrants in gray order
// (mh,nh) = (0,0),(0,1),(1,1),(1,0); 16 MFMA each. Per phase stage exactly one
// 128-row half-tile (2 x global_load_lds) into the half-slot freed one phase
// earlier; ONE vmcnt(6) per K-tile at the last phase (3 half-tiles = 6 loads
// stay in flight across barriers). Prologue stages 7 half-tiles.
// LDS 128 KiB, XOR-swizzled via pre-swizzled global source cols (rule #21).
__global__ __launch_bounds__(512, 2) void mega_gemm8(
    const bf16_t* __restrict__ Wv, const bf16_t* __restrict__ Wq,
    const bf16_t* __restrict__ Wk, const bf16_t* __restrict__ Bx,
    bf16_t* __restrict__ v_out, float* __restrict__ q_out, float* __restrict__ k_out,
    const float* __restrict__ v_scale, const float* __restrict__ v_shift,
    const float* __restrict__ q_scale, const float* __restrict__ q_shift,
    const float* __restrict__ k_scale, const float* __restrict__ k_shift)
{
    __shared__ __align__(16) bf16_t Ld[65536];   // A[2][16384] | B[2][16384] @32768

    const int tid  = threadIdx.x;
    const int lane = tid & 63;
    const int wid  = tid >> 6;
    const int wr   = wid >> 2;        // 0..1  (M half within quadrant rows)
    const int wc   = wid & 3;         // 0..3  (N quarter within quadrant cols)

    // XCD-aware bijective swizzle (nwg = 160, %8 == 0; 20 tiles per XCD)
    const int lin  = blockIdx.y * 4 + blockIdx.x;
    const int tile = (lin & 7) * 20 + (lin >> 3);
    const int trow = tile >> 2;
    const int col0 = (tile & 3) * 256;

    const bf16_t* Ag; const float* s0; const float* s1; int arow, path;
    if (trow < 32)      { Ag = Wv; arow = trow * 256;        s0 = v_scale; s1 = v_shift; path = 0; }
    else if (trow < 36) { Ag = Wq; arow = trow * 256 - 8192; s0 = q_scale; s1 = q_shift; path = 1; }
    else                { Ag = Wk; arow = trow * 256 - 9216; s0 = k_scale; s1 = k_shift; path = 2; }

    // staging: half-tile = 128 rows x 64 cols bf16 = 16 KB = 512 thr x 16B x 2
    const int ar0 = tid >> 3;                                  // row 0..63 in 64-chunk
    const int o0  = tid * 8;                                   // LDS elem offset
    const int csw = (((tid & 7) ^ ((tid >> 3) & 7)) << 3);     // pre-swizzled src col

    // read geometry
    const int lr   = lane & 15;
    const int hi8  = (lane >> 4) * 8;
    const int rsw  = (lane & 7) << 3;                          // read-side XOR (row&7 == lane&7)
    const int ck0  = hi8 ^ rsw;                                // kk=0 col
    const int ck1  = (32 + hi8) ^ rsw;                         // kk=1 col
    const int aRow = wr * 64 + lr;                             // row within A half
    const int bRow = wc * 32 + lr;                             // row within B half

    bf16x8 av[4][2];        // [fi][kk], current mh
    bf16x8 bv[2][2][2];     // [nh][fj][kk], both nh kept live
    f32x4  acc[2][2][4][2]; // [mh][nh][fi][fj]
    #pragma unroll
    for (int mh = 0; mh < 2; ++mh)
        #pragma unroll
        for (int nh = 0; nh < 2; ++nh)
            #pragma unroll
            for (int fi = 0; fi < 4; ++fi)
                #pragma unroll
                for (int fj = 0; fj < 2; ++fj)
                    acc[mh][nh][fi][fj] = (f32x4){0.f, 0.f, 0.f, 0.f};

#define STAGE_AH(BUF, H, KB) do {                                                             \
    gload_lds16(Ag + (size_t)(arow + (H)*128 + ar0     ) * CDIM + (KB) + csw,                 \
                Ld + (BUF)*16384 + (H)*8192 + o0);                                            \
    gload_lds16(Ag + (size_t)(arow + (H)*128 + ar0 + 64) * CDIM + (KB) + csw,                 \
                Ld + (BUF)*16384 + (H)*8192 + o0 + 4096);                                     \
} while (0)

#define STAGE_BH(BUF, H, KB) do {                                                             \
    gload_lds16(Bx + (size_t)(col0 + (H)*128 + ar0     ) * CDIM + (KB) + csw,                 \
                Ld + 32768 + (BUF)*16384 + (H)*8192 + o0);                                    \
    gload_lds16(Bx + (size_t)(col0 + (H)*128 + ar0 + 64) * CDIM + (KB) + csw,                 \
                Ld + 32768 + (BUF)*16384 + (H)*8192 + o0 + 4096);                             \
} while (0)

#define RD_A(BUF, MH) do {                                                                    \
    _Pragma("unroll") for (int fi = 0; fi < 4; ++fi) {                                        \
        av[fi][0] = *(const bf16x8*)(Ld + (BUF)*16384 + ((MH)*128 + aRow + fi*16)*64 + ck0);  \
        av[fi][1] = *(const bf16x8*)(Ld + (BUF)*16384 + ((MH)*128 + aRow + fi*16)*64 + ck1);  \
    }                                                                                         \
} while (0)

#define RD_B(BUF, NH) do {                                                                    \
    _Pragma("unroll") for (int fj = 0; fj < 2; ++fj) {                                        \
        bv[NH][fj][0] = *(const bf16x8*)(Ld + 32768 + (BUF)*16384 +                           \
                                         ((NH)*128 + bRow + fj*16)*64 + ck0);                 \
        bv[NH][fj][1] = *(const bf16x8*)(Ld + 32768 + (BUF)*16384 +                           \
                                         ((NH)*128 + bRow + fj*16)*64 + ck1);                 \
    }                                                                                         \
} while (0)

#define MMA(MH, NH) do {                                                                      \
    __builtin_amdgcn_s_setprio(1);                                                            \
    _Pragma("unroll") for (int kk = 0; kk < 2; ++kk)                                          \
        _Pragma("unroll") for (int fi = 0; fi < 4; ++fi)                                      \
            _Pragma("unroll") for (int fj = 0; fj < 2; ++fj)                                  \
                acc[MH][NH][fi][fj] = __builtin_amdgcn_mfma_f32_16x16x32_bf16(                \
                    av[fi][kk], bv[NH][fj][kk], acc[MH][NH][fi][fj], 0, 0, 0);                \
    __builtin_amdgcn_s_setprio(0);                                                            \
} while (0)

#define SYNC_TOP do {                                                                         \
    __builtin_amdgcn_s_barrier();                                                             \
    asm volatile("s_waitcnt lgkmcnt(0)" ::: "memory");                                        \
    __builtin_amdgcn_sched_barrier(0);                                                        \
} while (0)

#define SYNC_END do {                                                                         \
    __builtin_amdgcn_s_barrier();                                                             \
} while (0)

// One K-tile: 4 quadrant phases. DO_S2: stage tile T+2 (j1..j3). VM: 6 / 0 / -1(none).
#define KTILE(BUF, T, DO_S2, VM) do {                                                         \
    /* j0: quad (0,0) */                                                                      \
    RD_A(BUF, 0); RD_B(BUF, 0);                                                               \
    if ((T) + 1 < NT8) STAGE_BH((BUF)^1, 1, ((T)+1)*64);                                      \
    SYNC_TOP; MMA(0, 0); SYNC_END;                                                            \
    /* j1: quad (0,1) */                                                                      \
    RD_B(BUF, 1);                                                                             \
    if (DO_S2) STAGE_AH(BUF, 0, ((T)+2)*64);                                                  \
    SYNC_TOP; MMA(0, 1); SYNC_END;                                                            \
    /* j2: quad (1,1) */                                                                      \
    RD_A(BUF, 1);                                                                             \
    if (DO_S2) STAGE_BH(BUF, 0, ((T)+2)*64);                                                  \
    SYNC_TOP; MMA(1, 1); SYNC_END;                                                            \
    /* j3: quad (1,0) + per-tile vmcnt */                                                     \
    if (DO_S2) STAGE_AH(BUF, 1, ((T)+2)*64);                                                  \
    SYNC_TOP; MMA(1, 0);                                                                      \
    if ((VM) == 6)      { asm volatile("s_waitcnt vmcnt(6)" ::: "memory");                    \
                          __builtin_amdgcn_sched_barrier(0); }                                \
    else if ((VM) == 0) { asm volatile("s_waitcnt vmcnt(0)" ::: "memory");                    \
                          __builtin_amdgcn_sched_barrier(0); }                                \
    SYNC_END;                                                                                 \
} while (0)

    // prologue: tile0 all 4 halves + tile1's {Ah0,Bh0,Ah1} = 7 half-tiles (14 loads)
    STAGE_AH(0, 0, 0); STAGE_BH(0, 0, 0); STAGE_AH(0, 1, 0); STAGE_BH(0, 1, 0);
    STAGE_AH(1, 0, 64); STAGE_BH(1, 0, 64); STAGE_AH(1, 1, 64);
    asm volatile("s_waitcnt vmcnt(6)" ::: "memory");   // tile0 landed; 3 halves in flight
    __builtin_amdgcn_sched_barrier(0);
    __builtin_amdgcn_s_barrier();

    for (int t = 0; t < NT8 - 2; t += 2) {
        KTILE(0, t,     1, 6);
        KTILE(1, t + 1, 1, 6);
    }
    KTILE(0, NT8 - 2, 0, 0);   // stages only Bh1(127); drain
    KTILE(1, NT8 - 1, 0, -1);  // final tile: no stage, no wait

#undef KTILE
#undef SYNC_END
#undef SYNC_TOP
#undef MMA
#undef RD_B
#undef RD_A
#undef STAGE_BH
#undef STAGE_AH

    // epilogue: C/D layout col = lane&15, row = (lane>>4)*4 + r
    const int cq = (lane >> 4) * 4;
    #pragma unroll
    for (int mh = 0; mh < 2; ++mh) {
        #pragma unroll
        for (int nh = 0; nh < 2; ++nh) {
            #pragma unroll
            for (int fi = 0; fi < 4; ++fi) {
                #pragma unroll
                for (int fj = 0; fj < 2; ++fj) {
                    const int j = col0 + nh * 128 + wc * 32 + fj * 16 + lr;
                    #pragma unroll
                    for (int r = 0; r < 4; ++r) {
                        const int il = arow + mh * 128 + wr * 64 + fi * 16 + cq + r;
                        float vv = acc[mh][nh][fi][fj][r] * s0[il] + s1[il];
                        if (path == 0)      v_out[(size_t)il * NDIM + j] = (__bf16)vv;
                        else if (path == 1) q_out[(size_t)il * NDIM + j] = vv;
                        else                k_out[(size_t)il * NDIM + j] = vv;
                    }
                }
            }
        }
    }
}

// ---------------------------------------------------------------------------
// bt-GEMM: C[i,j] = sum_k A[i,k] * B[j,k]. XCD-swizzled xy grid; optional
// split-K via gridDim.z (each z writes its own partial plane C + z*M*N).
// EPI: 2 = v*(1/1023)/(e0[j]*e1[j])  -> ppmcc partial
//      3 = gs[0]*v + e0[i*N+j]       -> gamma*out + x
template <int EPI, typename OutT>
__global__ __launch_bounds__(256) void gemm_bt(
    const bf16_t* __restrict__ A, const bf16_t* __restrict__ B,
    OutT* __restrict__ C, int M, int N, int K,
    const float* __restrict__ e0, const float* __restrict__ e1,
    const float* __restrict__ gs)
{
    const int gx = gridDim.x;
    const int nwg = gx * gridDim.y;
    const int lin = blockIdx.y * gx + blockIdx.x;
    int tile = lin;
    if ((nwg & 7) == 0) tile = (lin & 7) * (nwg >> 3) + (lin >> 3);
    const int row0 = (tile / gx) * 128;
    const int col0 = (tile % gx) * 128;

    const int Ks  = K / gridDim.z;
    const int kb0 = blockIdx.z * Ks;
    const int kb1 = kb0 + Ks;
    OutT* Cz = C + (size_t)blockIdx.z * M * N;

    const int tid = threadIdx.x;
    __shared__ __align__(16) bf16_t As[2 * 4096];
    __shared__ __align__(16) bf16_t Bs[2 * 4096];

    const int lane = tid & 63;
    const int w    = tid >> 6;
    const int wm   = (w >> 1) * 64;
    const int wn   = (w & 1) * 64;
    const int lr   = lane & 15;
    const int kg   = (lane >> 4) * 8;

    f32x4 acc[4][4];
    #pragma unroll
    for (int a_ = 0; a_ < 4; ++a_)
        #pragma unroll
        for (int b_ = 0; b_ < 4; ++b_)
            acc[a_][b_] = (f32x4){0.f, 0.f, 0.f, 0.f};

    const int eA = tid * 8;
    const int eB = (256 + tid) * 8;
    const int rA = eA >> 5, cA = eA & 31;
    const int rB = eB >> 5, cB = eB & 31;

#define BT_STAGE(buf, kb)                                                       \
    do {                                                                        \
        gload_lds16(A + (size_t)(row0 + rA) * K + (kb) + cA, As + (buf)*4096 + eA); \
        gload_lds16(A + (size_t)(row0 + rB) * K + (kb) + cB, As + (buf)*4096 + eB); \
        gload_lds16(B + (size_t)(col0 + rA) * K + (kb) + cA, Bs + (buf)*4096 + eA); \
        gload_lds16(B + (size_t)(col0 + rB) * K + (kb) + cB, Bs + (buf)*4096 + eB); \
    } while (0)

    BT_STAGE(0, kb0);
    __syncthreads();
    int cur = 0;
    for (int kb = kb0; kb < kb1; kb += 32) {
        if (kb + 32 < kb1) BT_STAGE(cur ^ 1, kb + 32);
        const bf16_t* Ac = As + cur * 4096;
        const bf16_t* Bc = Bs + cur * 4096;

        bf16x8 av[4], bv[4];
        #pragma unroll
        for (int mi = 0; mi < 4; ++mi)
            av[mi] = *(const bf16x8*)(Ac + (wm + mi * 16 + lr) * 32 + kg);
        #pragma unroll
        for (int ni = 0; ni < 4; ++ni)
            bv[ni] = *(const bf16x8*)(Bc + (wn + ni * 16 + lr) * 32 + kg);

        #pragma unroll
        for (int mi = 0; mi < 4; ++mi)
            #pragma unroll
            for (int ni = 0; ni < 4; ++ni)
                acc[mi][ni] = __builtin_amdgcn_mfma_f32_16x16x32_bf16(
                    av[mi], bv[ni], acc[mi][ni], 0, 0, 0);
        __syncthreads();
        cur ^= 1;
    }
#undef BT_STAGE

    float g = 0.f;
    if (EPI == 3) g = gs[0];
    const int cr = (lane >> 4) * 4;
    #pragma unroll
    for (int mi = 0; mi < 4; ++mi) {
        #pragma unroll
        for (int ni = 0; ni < 4; ++ni) {
            const int j = col0 + wn + ni * 16 + lr;
            float s0 = 0.f, s1 = 0.f;
            if (EPI == 2) { s0 = e0[j]; s1 = e1[j]; }
            #pragma unroll
            for (int r = 0; r < 4; ++r) {
                const int i = row0 + wm + mi * 16 + cr + r;
                float v = acc[mi][ni][r];
                if (EPI == 2)      v = v * (1.0f / 1023.0f) / (s0 * s1);
                else if (EPI == 3) v = g * v + e0[(size_t)i * N + j];
                Cz[(size_t)i * N + j] = (OutT)v;
            }
        }
    }
}

// ---------------------------------------------------------------------------
// Row mean/std (ddof=0) of q_on / k_on (each 1024 x 1024 fp32). One wave/row.
__global__ __launch_bounds__(256) void rowstats(
    const float* __restrict__ Q, const float* __restrict__ Km,
    float* __restrict__ qmean, float* __restrict__ qstd,
    float* __restrict__ kmean, float* __restrict__ kstd)
{
    const int wid  = blockIdx.x * 4 + (threadIdx.x >> 6);
    const int lane = threadIdx.x & 63;
    const float* src = (wid < 1024) ? (Q + (size_t)wid * NDIM)
                                    : (Km + (size_t)(wid - 1024) * NDIM);
    float s = 0.f, s2 = 0.f;
    #pragma unroll
    for (int p = 0; p < 4; ++p) {
        float4 v = *(const float4*)(src + p * 256 + lane * 4);
        s  += v.x + v.y + v.z + v.w;
        s2 += v.x * v.x + v.y * v.y + v.z * v.z + v.w * v.w;
    }
    #pragma unroll
    for (int o = 32; o; o >>= 1) { s += __shfl_xor(s, o); s2 += __shfl_xor(s2, o); }
    if (lane == 0) {
        float m   = s / 1024.f;
        float var = fmaxf(s2 / 1024.f - m * m, 0.f);
        if (wid < 1024) { qmean[wid] = m; qstd[wid] = sqrtf(var); }
        else            { kmean[wid - 1024] = m; kstd[wid - 1024] = sqrtf(var); }
    }
}

// ---------------------------------------------------------------------------
// Center by row mean, transpose (o,n)->(n,o), convert bf16. z selects q/k.
__global__ __launch_bounds__(256) void center_tr(
    const float* __restrict__ Q, const float* __restrict__ qmu, bf16_t* __restrict__ qc,
    const float* __restrict__ Km, const float* __restrict__ kmu, bf16_t* __restrict__ kc)
{
    __shared__ float t[32][33];
    const float* M  = blockIdx.z ? Km  : Q;
    const float* mu = blockIdx.z ? kmu : qmu;
    bf16_t* O       = blockIdx.z ? kc  : qc;
    const int o0 = blockIdx.y * 32, n0 = blockIdx.x * 32;
    const int tx = threadIdx.x, ty = threadIdx.y; // block (32,8)
    #pragma unroll
    for (int i = 0; i < 4; ++i) {
        const int o = o0 + ty + i * 8;
        t[ty + i * 8][tx] = M[(size_t)o * NDIM + n0 + tx] - mu[o];
    }
    __syncthreads();
    #pragma unroll
    for (int i = 0; i < 4; ++i)
        O[(size_t)(n0 + ty + i * 8) * C8D + o0 + tx] = (__bf16)t[tx][ty + i * 8];
}

// ---------------------------------------------------------------------------
// Row softmax over the sum of 4 split-K partial P planes -> bf16 A0.
__global__ __launch_bounds__(256) void softmax_rows(const float* __restrict__ P,
                                                    bf16_t* __restrict__ O) {
    const int row = blockIdx.x;
    const int tid = threadIdx.x;
    const size_t PL = (size_t)NDIM * NDIM / 4;   // plane size in float4 units
    const size_t u  = (size_t)row * (NDIM / 4) + tid;
    const float4* B = (const float4*)P;
    float4 p0 = B[u], p1 = B[u + PL], p2 = B[u + 2 * PL], p3 = B[u + 3 * PL];
    float4 v = { p0.x + p1.x + p2.x + p3.x, p0.y + p1.y + p2.y + p3.y,
                 p0.z + p1.z + p2.z + p3.z, p0.w + p1.w + p2.w + p3.w };
    float mx = fmaxf(fmaxf(v.x, v.y), fmaxf(v.z, v.w));
    #pragma unroll
    for (int o = 32; o; o >>= 1) mx = fmaxf(mx, __shfl_xor(mx, o));
    __shared__ float red[8];
    const int w = tid >> 6, lane = tid & 63;
    if (lane == 0) red[w] = mx;
    __syncthreads();
    mx = fmaxf(fmaxf(red[0], red[1]), fmaxf(red[2], red[3]));
    float e0 = __expf(v.x - mx), e1 = __expf(v.y - mx);
    float e2 = __expf(v.z - mx), e3 = __expf(v.w - mx);
    float s = e0 + e1 + e2 + e3;
    #pragma unroll
    for (int o = 32; o; o >>= 1) s += __shfl_xor(s, o);
    if (lane == 0) red[4 + w] = s;
    __syncthreads();
    s = red[4] + red[5] + red[6] + red[7];
    const float inv = 1.0f / s;
    bf16x4 o4 = { (__bf16)(e0 * inv), (__bf16)(e1 * inv),
                  (__bf16)(e2 * inv), (__bf16)(e3 * inv) };
    ((bf16x4*)(O + (size_t)row * NDIM))[tid] = o4;
}

// ---------------------------------------------------------------------------
extern "C" void kernel_launch(void* const* d_in, const int* in_sizes, int n_in,
                              void* d_out, int out_size, void* d_ws, size_t ws_size,
                              hipStream_t stream)
{
    const float* x       = (const float*)d_in[0];
    const float* Wq      = (const float*)d_in[1];
    const float* Wk      = (const float*)d_in[2];
    const float* Wv      = (const float*)d_in[3];
    const float* q_scale = (const float*)d_in[4];
    const float* q_shift = (const float*)d_in[5];
    const float* k_scale = (const float*)d_in[6];
    const float* k_shift = (const float*)d_in[7];
    const float* v_scale = (const float*)d_in[8];
    const float* v_shift = (const float*)d_in[9];
    const float* gamma   = (const float*)d_in[10];
    float* out = (float*)d_out;

    // workspace layout (~230 MB)
    char* w = (char*)d_ws;
    bf16_t* Wv_b = (bf16_t*)w; w += (size_t)CDIM * CDIM * 2;
    bf16_t* Wq_b = (bf16_t*)w; w += (size_t)C8D  * CDIM * 2;
    bf16_t* Wk_b = (bf16_t*)w; w += (size_t)C8D  * CDIM * 2;
    bf16_t* xT   = (bf16_t*)w; w += (size_t)NDIM * CDIM * 2;
    bf16_t* v_b  = (bf16_t*)w; w += (size_t)CDIM * NDIM * 2;
    float*  q_on = (float*) w; w += (size_t)C8D * NDIM * 4;
    float*  k_on = (float*) w; w += (size_t)C8D * NDIM * 4;
    float*  P    = (float*) w; w += (size_t)4 * NDIM * NDIM * 4;  // 4 split-K planes
    bf16_t* qc   = (bf16_t*)w; w += (size_t)NDIM * C8D * 2;
    bf16_t* kc   = (bf16_t*)w; w += (size_t)NDIM * C8D * 2;
    bf16_t* A0   = (bf16_t*)w; w += (size_t)NDIM * NDIM * 2;
    float*  qmean = (float*)w; w += C8D * 4;
    float*  qstd  = (float*)w; w += C8D * 4;
    float*  kmean = (float*)w; w += C8D * 4;
    float*  kstd  = (float*)w; w += C8D * 4;

    // 1. converts
    cvt_bf16_k<<<2048, 256, 0, stream>>>(Wv, Wv_b, (int)((size_t)CDIM * CDIM / 8));
    cvt_bf16_k<<<2048, 256, 0, stream>>>(Wq, Wq_b, C8D * CDIM / 8);
    cvt_bf16_k<<<2048, 256, 0, stream>>>(Wk, Wk_b, C8D * CDIM / 8);
    transpose_cvt_x<<<dim3(NDIM / 32, CDIM / 32), dim3(32, 8), 0, stream>>>(x, xT);

    // 2. mega-GEMM, 256^2 4-phase counted-vmcnt pipeline (160 blocks x 512 thr)
    mega_gemm8<<<dim3(4, MSTACK / 256), 512, 0, stream>>>(
        Wv_b, Wq_b, Wk_b, xT, v_b, q_on, k_on,
        v_scale, v_shift, q_scale, q_shift, k_scale, k_shift);

    // 3. row stats of q_on / k_on (2048 waves)
    rowstats<<<512, 256, 0, stream>>>(q_on, k_on, qmean, qstd, kmean, kstd);

    // 4. center + transpose + bf16
    center_tr<<<dim3(32, 32, 2), dim3(32, 8), 0, stream>>>(
        q_on, qmean, qc, k_on, kmean, kc);

    // 5. P[z] = (qc . kc^T)_z / 1023 / (qstd[j] * kstd[j]), split-K x4 (256 blocks)
    gemm_bt<2, float><<<dim3(NDIM / 128, NDIM / 128, 4), 256, 0, stream>>>(
        qc, kc, P, NDIM, NDIM, C8D, qstd, kstd, nullptr);

    // 6. row softmax over summed partials -> A0 (bf16)
    softmax_rows<<<NDIM, 256, 0, stream>>>(P, A0);

    // 7. out = gamma * (v . A0^T) + x
    gemm_bt<3, float><<<dim3(NDIM / 128, CDIM / 128, 1), 256, 0, stream>>>(
        v_b, A0, out, CDIM, NDIM, NDIM, x, x, gamma);
}